// Round 5
// baseline (346.416 us; speedup 1.0000x reference)
//
#include <hip/hip_runtime.h>

// Involution2d: B=8, C=256, G=4 (Cpg=64), H=W=Ho=Wo=64, K=7, PAD=3, STRIDE=1.
// out[b, g*64+c, y, x] = sum_{kh,kw} in[b, g*64+c, y+kh-3, x+kw-3] * w[b,g,kh,kw,y,x] + bias[g*64+c]
//
// Round-5: identical design to round-4 (which died to a container infra
// failure, not a kernel verdict). Round-0 geometry with its three flaws fixed:
//  FLAW 1 (biggest): round-0 held w4[49] float4 "in registers" but VGPR_Count
//    was 128 < 196 needed -> compiler rematerialized weight loads PER CHANNEL
//    from L2 (serial latency, why VALUBusy was 19%). Fix: waves_per_eu(2,2)
//    gives a 256-VGPR budget AND opaque asm pins on every weight component
//    make remat impossible. Live set ~240 regs fits.
//  FLAW 2: 31 barriers/block (2 per channel, single LDS buffer). Fix:
//    ping-pong LDS buffers of NSTG=2 channels -> 1 barrier per 2 channels,
//    with next-group global loads issued before the current group's 392 FMAs.
//  FLAW 3: stride-71 unaligned LDS -> scalar ds_read. Fix: stride 72,
//    halo-at-col-4 layout: all b128 both ways, bank-phase uniform
//    (writes: tid%8; reads: (4ch+2(ty+kh)+tx)%8 -> uniform over 64 lanes).
// Checks this round: VGPR ~240-256 (residency proof), WRITE_SIZE ~33MB
// (no spill), dur_us 20-28, VALUBusy 45-60%.

#define BLK_X 16
#define BLK_Y 8
#define NTHR  128
#define CH_PER_BLK 16
#define NSTG 2                    // channels per staging group
#define NGRP (CH_PER_BLK / NSTG)  // 8
#define S_ROWS 14                 // 8 output rows + 6 halo
#define S_STRIDE 72               // 18 float4/row; data cols 4..67, zeros 0..3/68..71
#define S_CH (S_ROWS * S_STRIDE)  // 1008 floats per channel
#define SEGS (S_ROWS * 18)        // 252 16B segments per channel

// issue global loads for staging group grp_ into registers dst[NSTG][2]
#define LOADG(dst, grp_) do {                                              \
    _Pragma("unroll")                                                      \
    for (int ch_ = 0; ch_ < NSTG; ++ch_) {                                 \
        const float* p_ = inb + (size_t)(c0 + (grp_) * NSTG + ch_) * 4096; \
        _Pragma("unroll")                                                  \
        for (int j_ = 0; j_ < 2; ++j_) {                                   \
            int e_ = tid + j_ * NTHR;                                      \
            float4 v_ = make_float4(0.f, 0.f, 0.f, 0.f);                   \
            if (e_ < SEGS) {                                               \
                int row_ = e_ / 18;                                        \
                int t_   = e_ - row_ * 18;                                 \
                int gy_  = Y0 + row_ - 3;                                  \
                if (t_ >= 1 && t_ <= 16 && gy_ >= 0 && gy_ < 64)           \
                    v_ = *(const float4*)(p_ + gy_ * 64 + (t_ - 1) * 4);   \
            }                                                              \
            dst[ch_][j_] = v_;                                             \
        }                                                                  \
    }                                                                      \
} while (0)

// write registers src[NSTG][2] into LDS buffer bufp (linear seg layout)
#define WRITE_STAGE(bufp, src) do {                                        \
    _Pragma("unroll")                                                      \
    for (int ch_ = 0; ch_ < NSTG; ++ch_) {                                 \
        _Pragma("unroll")                                                  \
        for (int j_ = 0; j_ < 2; ++j_) {                                   \
            int e_ = tid + j_ * NTHR;                                      \
            if (e_ < SEGS)                                                 \
                *(float4*)((bufp) + ch_ * S_CH + e_ * 4) = src[ch_][j_];   \
        }                                                                  \
    }                                                                      \
} while (0)

__global__ __launch_bounds__(NTHR)
__attribute__((amdgpu_waves_per_eu(2, 2)))
void involution_kernel(const float* __restrict__ in,
                       const float* __restrict__ w,
                       const float* __restrict__ bias,
                       float* __restrict__ out) {
    __shared__ float lds[2][NSTG][S_CH];   // ping-pong, 16,128 B total

    const int tx  = threadIdx.x;           // 0..15 (x-quad)
    const int ty  = threadIdx.y;           // 0..7  (row)
    const int tid = ty * BLK_X + tx;
    const int x0  = tx * 4;
    const int Y0  = blockIdx.x * BLK_Y;
    const int y   = Y0 + ty;
    const int c0  = blockIdx.y * CH_PER_BLK;
    const int bz  = blockIdx.z;            // b*4 + g
    const int g   = bz & 3;

    const float* inb  = in  + (size_t)bz * 64 * 4096;
    float*       outb = out + (size_t)bz * 64 * 4096;
    const float* wb   = w   + (size_t)bz * 49 * 4096 + y * 64 + x0;

    // ---- issue all weight loads (49 coalesced dwordx4), then group-0 staging
    float4 w4[49];
    #pragma unroll
    for (int k = 0; k < 49; ++k)
        w4[k] = *(const float4*)(wb + (size_t)k * 4096);

    float4 pf[NSTG][2];
    LOADG(pf, 0);

    // bias for this block's 16 channels (hoisted out of the channel loop)
    float bvs[CH_PER_BLK];
    #pragma unroll
    for (int c = 0; c < CH_PER_BLK; ++c)
        bvs[c] = bias[g * 64 + c0 + c];

    // ---- pin weights: opaque asm makes rematerialization impossible; with
    //      the 256-VGPR budget they stay resident for all 16 channels.
    #pragma unroll
    for (int k = 0; k < 49; ++k) {
        asm volatile("" : "+v"(w4[k].x), "+v"(w4[k].y),
                          "+v"(w4[k].z), "+v"(w4[k].w));
    }

    WRITE_STAGE(&lds[0][0][0], pf);
    __syncthreads();

    #pragma unroll 1
    for (int grp = 0; grp < NGRP; ++grp) {
        float* cur = &lds[grp & 1][0][0];
        float* nxt = &lds[(grp + 1) & 1][0][0];
        const bool more = (grp + 1 < NGRP);

        if (more) LOADG(pf, grp + 1);      // issue next-group loads early

        // ---- compute NSTG channels from cur (hides the loads above) ----
        #pragma unroll
        for (int ch = 0; ch < NSTG; ++ch) {
            const int c = grp * NSTG + ch;
            float a0 = 0.f, a1 = 0.f, a2 = 0.f, a3 = 0.f;
            #pragma unroll
            for (int kh = 0; kh < 7; ++kh) {
                const float* lr = cur + ch * S_CH + (ty + kh) * S_STRIDE + x0;
                float4 va = *(const float4*)(lr);
                float4 vb = *(const float4*)(lr + 4);
                float4 vc = *(const float4*)(lr + 8);
                float vals[12] = {va.x, va.y, va.z, va.w,
                                  vb.x, vb.y, vb.z, vb.w,
                                  vc.x, vc.y, vc.z, vc.w};
                #pragma unroll
                for (int kw = 0; kw < 7; ++kw) {
                    const float4 wv = w4[kh * 7 + kw];
                    a0 += vals[kw + 1] * wv.x;
                    a1 += vals[kw + 2] * wv.y;
                    a2 += vals[kw + 3] * wv.z;
                    a3 += vals[kw + 4] * wv.w;
                }
            }
            const float bv = bvs[c];
            float4 o;
            o.x = a0 + bv; o.y = a1 + bv; o.z = a2 + bv; o.w = a3 + bv;
            *(float4*)(outb + (size_t)(c0 + c) * 4096 + y * 64 + x0) = o;
        }

        if (more) {
            WRITE_STAGE(nxt, pf);          // pf consumed; all cur reads done
            __syncthreads();               // staging visible for next iter
        }
    }
}

extern "C" void kernel_launch(void* const* d_in, const int* in_sizes, int n_in,
                              void* d_out, int out_size, void* d_ws, size_t ws_size,
                              hipStream_t stream) {
    const float* in   = (const float*)d_in[0];  // (8,256,64,64)
    const float* wgt  = (const float*)d_in[1];  // (8,4,7,7,64,64)
    const float* bias = (const float*)d_in[2];  // (256,)
    float* out = (float*)d_out;                 // (8,256,64,64)

    dim3 block(BLK_X, BLK_Y, 1);                   // 128 threads = 2 waves
    dim3 grid(64 / BLK_Y, 64 / CH_PER_BLK, 32);    // (8, 4, 32) = 1024 blocks
    involution_kernel<<<grid, block, 0, stream>>>(in, wgt, bias, out);
}

// Round 6
// 125.289 us; speedup vs baseline: 2.7649x; 2.7649x over previous
//
#include <hip/hip_runtime.h>

// Involution2d: B=8, C=256, G=4 (Cpg=64), H=W=Ho=Wo=64, K=7, PAD=3, STRIDE=1.
// out[b, g*64+c, y, x] = sum_{kh,kw} in[b, g*64+c, y+kh-3, x+kw-3] * w[b,g,kh,kw,y,x] + bias[g*64+c]
//
// Round-6. Empirical law from r0-r5: the allocator caps at 128 VGPR; any
// design demanding more gets remat'd (r0), serialized (r1/r2), or spilled
// (r3/r5). This kernel's total demand ~101 regs:
//   wA[7]+wB[7] float4 = 56, acc 16, vals 12, bias 4, addr ~13.
//  - Weights STREAMED per kh, depth-2 ping-pong: kh+2's 7 loads issue right
//    after kh's compute -> one full step (~350cyc, 112 FMA + 12 ds_read) of
//    latency cover; each load serves 4 channels by construction.
//  - Input staged ONCE for all 4 channels (round-1 style, single barrier).
//  - LDS XOR swizzle kills the 12.55M conflict cycles measured in r1:
//    row stride = 24 float4 (mult of 8 -> row/ch drop out of bank phase);
//    slot(row,t) = row*24 + (t ^ (row&7)). Read phase over an 8-lane octet
//    = (tx+m)^(row&7) mod 8 -> bijection -> conflict-free b128, guaranteed.
//    Same swizzle on staging writes (consecutive-e octets stay bijective).

#define BLK_X 16
#define BLK_Y 16
#define NTHR  256
#define NC    4
#define ROWS  16                  // output rows per block (= BLK_Y)
#define S_ROWS 22                 // ROWS + 6 halo
#define ST_F4 24                  // float4 stride per staged row (swizzle space)
#define S_CH_F4 (S_ROWS * ST_F4)  // 528 float4 per channel
#define SEGS (S_ROWS * 18)        // 396 valid float4 per channel (cols 0..17)

// load 7 weight float4 for kernel row KH into buf (coalesced dwordx4)
#define LOADW(buf, KH) do {                                                 \
    _Pragma("unroll")                                                       \
    for (int kw_ = 0; kw_ < 7; ++kw_)                                       \
        buf[kw_] = *(const float4*)(wb + (size_t)((KH) * 7 + kw_) * 4096);  \
} while (0)

// one kh step: 4 channels x (3 swizzled b128 reads + 28 FMAs) with weights W
#define STEP(KH, W) do {                                                    \
    const int row_ = ty + (KH);          /* staged row 0..21 */             \
    const int xm_  = row_ & 7;                                              \
    _Pragma("unroll")                                                       \
    for (int ch_ = 0; ch_ < NC; ++ch_) {                                    \
        const float4* lp_ = lds4 + ch_ * S_CH_F4 + row_ * ST_F4;            \
        float4 v0_ = lp_[(tx + 0) ^ xm_];                                   \
        float4 v1_ = lp_[(tx + 1) ^ xm_];                                   \
        float4 v2_ = lp_[(tx + 2) ^ xm_];                                   \
        float vals_[12] = {v0_.x, v0_.y, v0_.z, v0_.w,                      \
                           v1_.x, v1_.y, v1_.z, v1_.w,                      \
                           v2_.x, v2_.y, v2_.z, v2_.w};                     \
        _Pragma("unroll")                                                   \
        for (int kw_ = 0; kw_ < 7; ++kw_) {                                 \
            acc[ch_][0] += vals_[kw_ + 1] * W[kw_].x;                       \
            acc[ch_][1] += vals_[kw_ + 2] * W[kw_].y;                       \
            acc[ch_][2] += vals_[kw_ + 3] * W[kw_].z;                       \
            acc[ch_][3] += vals_[kw_ + 4] * W[kw_].w;                       \
        }                                                                   \
    }                                                                       \
} while (0)

__global__ __launch_bounds__(NTHR, 4)
void involution_kernel(const float* __restrict__ in,
                       const float* __restrict__ w,
                       const float* __restrict__ bias,
                       float* __restrict__ out) {
    __shared__ float4 lds4[NC * S_CH_F4];   // 4*528*16 = 33,792 B

    const int tx  = threadIdx.x;            // 0..15 (x-quad)
    const int ty  = threadIdx.y;            // 0..15 (row)
    const int tid = ty * BLK_X + tx;
    const int x0  = tx * 4;
    const int Y0  = blockIdx.x * ROWS;
    const int y   = Y0 + ty;
    const int c0  = blockIdx.y * NC;
    const int bz  = blockIdx.z;             // b*4 + g
    const int g   = bz & 3;

    const float* inb  = in  + (size_t)bz * 64 * 4096;
    float*       outb = out + (size_t)bz * 64 * 4096;
    const float* wb   = w   + (size_t)bz * 49 * 4096 + y * 64 + x0;

    float4 wA[7], wB[7];
    LOADW(wA, 0);                 // kh=0 weights hide under staging

    // ---- stage NC channels once, swizzled, single barrier ----
    // valid cols t=0..17 (halo at t=0 and t=17 stays zero; data t=1..16
    // maps to gx = 4(t-1)); slot = row*24 + (t ^ (row&7)).
    #pragma unroll
    for (int ch = 0; ch < NC; ++ch) {
        const float* p = inb + (size_t)(c0 + ch) * 4096;
        #pragma unroll
        for (int j = 0; j < 2; ++j) {
            int e = tid + j * NTHR;          // 0..511, guard < 396
            if (e < SEGS) {
                int row = e / 18;
                int t   = e - row * 18;
                int gy  = Y0 + row - 3;
                float4 v = make_float4(0.f, 0.f, 0.f, 0.f);
                if (t >= 1 && t <= 16 && gy >= 0 && gy < 64)
                    v = *(const float4*)(p + gy * 64 + (t - 1) * 4);
                lds4[ch * S_CH_F4 + row * ST_F4 + (t ^ (row & 7))] = v;
            }
        }
    }

    float bvs[NC];
    #pragma unroll
    for (int c = 0; c < NC; ++c) bvs[c] = bias[g * 64 + c0 + c];

    LOADW(wB, 1);                 // kh=1 weights hide under the barrier
    __syncthreads();

    float acc[NC][4];
    #pragma unroll
    for (int c = 0; c < NC; ++c) {
        acc[c][0] = 0.f; acc[c][1] = 0.f; acc[c][2] = 0.f; acc[c][3] = 0.f;
    }

    // ---- depth-2 software-pipelined kh loop (fully unrolled, static names)
    STEP(0, wA);  LOADW(wA, 2);
    STEP(1, wB);  LOADW(wB, 3);
    STEP(2, wA);  LOADW(wA, 4);
    STEP(3, wB);  LOADW(wB, 5);
    STEP(4, wA);  LOADW(wA, 6);
    STEP(5, wB);
    STEP(6, wA);

    // ---- epilogue ----
    #pragma unroll
    for (int c = 0; c < NC; ++c) {
        float4 o;
        o.x = acc[c][0] + bvs[c];
        o.y = acc[c][1] + bvs[c];
        o.z = acc[c][2] + bvs[c];
        o.w = acc[c][3] + bvs[c];
        *(float4*)(outb + (size_t)(c0 + c) * 4096 + y * 64 + x0) = o;
    }
}

extern "C" void kernel_launch(void* const* d_in, const int* in_sizes, int n_in,
                              void* d_out, int out_size, void* d_ws, size_t ws_size,
                              hipStream_t stream) {
    const float* in   = (const float*)d_in[0];  // (8,256,64,64)
    const float* wgt  = (const float*)d_in[1];  // (8,4,7,7,64,64)
    const float* bias = (const float*)d_in[2];  // (256,)
    float* out = (float*)d_out;                 // (8,256,64,64)

    dim3 block(BLK_X, BLK_Y, 1);                 // 256 threads = 4 waves
    dim3 grid(64 / ROWS, 64 / NC, 32);           // (4, 16, 32) = 2048 blocks
    involution_kernel<<<grid, block, 0, stream>>>(in, wgt, bias, out);
}